// Round 8
// baseline (271.348 us; speedup 1.0000x reference)
//
#include <hip/hip_runtime.h>

#define DD 128   // feature dim
#define KY 512   // y columns (R * DD)
#define KT 640   // total GEMM K (KY + DD)
#define RR 4     // relations
#define CAPL 4   // log2 slot capacity per (relation,node) bucket
#define CAP (1 << CAPL)

typedef short short8 __attribute__((ext_vector_type(8)));
typedef float f32x4 __attribute__((ext_vector_type(4)));

__device__ __forceinline__ unsigned short f2bf(float f) {
  unsigned u = __float_as_uint(f);
  u += 0x7fffu + ((u >> 16) & 1u);   // round-to-nearest-even
  return (unsigned short)(u >> 16);
}

// ---- 1. fused prep: xcast (+zero row N) | wcast | fill_slots, by block range ----
// slot layout node-major: slot[n*64 + r*16 + pos]; deg node-major: deg[n*4 + r]
__global__ __launch_bounds__(256) void prep(const float* __restrict__ x,
                                            const float* __restrict__ weight,
                                            const float* __restrict__ loopw,
                                            const int* __restrict__ src,
                                            const int* __restrict__ dst,
                                            unsigned short* __restrict__ xb,
                                            unsigned short* __restrict__ wt,
                                            int* __restrict__ deg,
                                            int* __restrict__ slot,
                                            int N, int E, int XB, int WB) {
  int b = blockIdx.x;
  int t = threadIdx.x;
  if (b < XB) {
    // xcast: 8 floats per thread over N+1 rows (row N = zeros)
    int i = b * 256 + t;
    if (i >= (N + 1) * 16) return;
    int n = i >> 4;
    uint4 o = make_uint4(0, 0, 0, 0);
    if (n < N) {
      const float4* xp = (const float4*)x + (size_t)i * 2;
      float4 v0 = xp[0], v1 = xp[1];
      o.x = (unsigned)f2bf(v0.x) | ((unsigned)f2bf(v0.y) << 16);
      o.y = (unsigned)f2bf(v0.z) | ((unsigned)f2bf(v0.w) << 16);
      o.z = (unsigned)f2bf(v1.x) | ((unsigned)f2bf(v1.y) << 16);
      o.w = (unsigned)f2bf(v1.z) | ((unsigned)f2bf(v1.w) << 16);
    }
    ((uint4*)xb)[i] = o;
  } else if (b < XB + WB) {
    // wcast: stacked weights, transposed to [col][k]
    int i = (b - XB) * 256 + t;
    if (i >= DD * KT) return;
    int c = i / KT, k = i - c * KT;
    float v = (k < KY) ? weight[(size_t)(k >> 7) * DD * DD + (k & (DD - 1)) * DD + c]
                       : loopw[(size_t)(k - KY) * DD + c];
    wt[i] = f2bf(v);
  } else {
    // fill_slots: one atomic pass; slot store is non-temporal (no write-allocate)
    int i = (b - XB - WB) * 256 + t;
    if (i >= RR * E) return;
    int r = i / E;
    size_t bk = (size_t)dst[i] * RR + r;
    int pos = atomicAdd(deg + bk, 1);
    if (pos < CAP)
      __builtin_nontemporal_store(src[i], slot + (bk << CAPL) + pos);
  }
}

// ---- 2. gather-aggregate: one wave per node; slot ids via readlane (SGPR),
//         scalar validity selects, invalid -> zero row N; no masking VALU ----
__global__ __launch_bounds__(256) void gather_agg(const unsigned* __restrict__ xbu,
                                                  const int* __restrict__ slot,
                                                  const int* __restrict__ deg,
                                                  unsigned* __restrict__ yu,
                                                  int N) {
  int gid = blockIdx.x * 256 + threadIdx.x;
  int n = gid >> 6, lane = gid & 63;
  if (n >= N) return;

  // all 64 slot ids of this node in one coalesced 256B load (lane = r*16+i)
  int sv = slot[(size_t)n * 64 + lane];

  int4 dv = *(const int4*)(deg + (size_t)n * 4);
  int cn[RR], ct[RR];
  ct[0] = __builtin_amdgcn_readfirstlane(dv.x);
  ct[1] = __builtin_amdgcn_readfirstlane(dv.y);
  ct[2] = __builtin_amdgcn_readfirstlane(dv.z);
  ct[3] = __builtin_amdgcn_readfirstlane(dv.w);
#pragma unroll
  for (int r = 0; r < RR; r++) cn[r] = ct[r] > CAP ? CAP : ct[r];

  float ax[RR], ay[RR];
#pragma unroll
  for (int r = 0; r < RR; r++) { ax[r] = 0.f; ay[r] = 0.f; }

  int m = max(max(cn[0], cn[1]), max(cn[2], cn[3]));
  for (int i0 = 0; i0 < m; i0 += 4) {
    unsigned vv[4][RR];
#pragma unroll
    for (int u = 0; u < 4; u++) {
#pragma unroll
      for (int r = 0; r < RR; r++) {
        int i = i0 + u;
        int s = __builtin_amdgcn_readlane(sv, (r << 4) | (i & 15));  // SGPR
        s = (i < cn[r]) ? s : N;   // uniform cond -> s_cselect, N = zero row
        vv[u][r] = xbu[(size_t)s * 64 + lane];
      }
    }
#pragma unroll
    for (int u = 0; u < 4; u++)
#pragma unroll
      for (int r = 0; r < RR; r++) {
        ax[r] += __uint_as_float(vv[u][r] << 16);
        ay[r] += __uint_as_float(vv[u][r] & 0xffff0000u);
      }
  }
#pragma unroll
  for (int r = 0; r < RR; r++) {
    float inv = 1.0f / (float)max(ct[r], 1);
    yu[(size_t)n * (KY / 2) + r * 64 + lane] =
        (unsigned)f2bf(ax[r] * inv) | ((unsigned)f2bf(ay[r] * inv) << 16);
  }
}

// ---- 3. fused bf16 MFMA GEMM: out = relu([y|xb][N,640] @ Wcat + bias) ----
// 256 threads = 4 waves; wave computes 32 rows x 128 cols (16 MFMA / 10 ds_read
// per k-step). 128-row tile, 20 KB LDS -> ~12 waves/CU occupancy.
#define LDA 40  // padded LDS row stride (ushorts)
__global__ __launch_bounds__(256) void gemm_mfma(const unsigned short* __restrict__ y,
                                                 const unsigned short* __restrict__ xb,
                                                 const unsigned short* __restrict__ wt,
                                                 const float* __restrict__ bias,
                                                 float* __restrict__ out, int N) {
  __shared__ unsigned short As[128 * LDA];
  __shared__ unsigned short Bs[128 * LDA];
  int t = threadIdx.x;
  int w = t >> 6, lane = t & 63;
  int row0 = blockIdx.x * 128;

  f32x4 acc[2][8];
#pragma unroll
  for (int i = 0; i < 2; i++)
#pragma unroll
    for (int c = 0; c < 8; c++) acc[i][c] = (f32x4){0.f, 0.f, 0.f, 0.f};

  for (int k0 = 0; k0 < KT; k0 += 32) {
    bool sely = (k0 < KY);
    // stage A (i=0,1) and B (i=2,3): 1024 uint4 across 256 threads
#pragma unroll
    for (int i = 0; i < 4; ++i) {
      int idx = t + i * 256;
      int row = (idx & 511) >> 2;
      int seg = (idx & 3) * 8;
      if (idx < 512) {
        int gr = row0 + row;
        uint4 va = make_uint4(0, 0, 0, 0);
        if (gr < N) {
          const unsigned short* ap =
              sely ? (y + (size_t)gr * KY + k0 + seg)
                   : (xb + (size_t)gr * DD + (k0 - KY) + seg);
          va = *(const uint4*)ap;
        }
        *(uint4*)(As + row * LDA + seg) = va;
      } else {
        *(uint4*)(Bs + row * LDA + seg) =
            *(const uint4*)(wt + (size_t)row * KT + k0 + seg);
      }
    }
    __syncthreads();
    int q8 = (lane >> 4) * 8;
    int m = lane & 15;
    short8 a[2], b[8];
#pragma unroll
    for (int i = 0; i < 2; ++i)
      a[i] = *(const short8*)(As + (w * 32 + i * 16 + m) * LDA + q8);
#pragma unroll
    for (int c = 0; c < 8; ++c)
      b[c] = *(const short8*)(Bs + (c * 16 + m) * LDA + q8);
#pragma unroll
    for (int i = 0; i < 2; ++i)
#pragma unroll
      for (int c = 0; c < 8; ++c)
        acc[i][c] = __builtin_amdgcn_mfma_f32_16x16x32_bf16(a[i], b[c], acc[i][c], 0, 0, 0);
    __syncthreads();
  }

  float bv[8];
#pragma unroll
  for (int c = 0; c < 8; ++c) bv[c] = bias[c * 16 + (lane & 15)];
#pragma unroll
  for (int i = 0; i < 2; ++i) {
    int rbase = row0 + w * 32 + i * 16 + (lane >> 4) * 4;
#pragma unroll
    for (int v = 0; v < 4; ++v) {
      int gr = rbase + v;
      if (gr < N) {
#pragma unroll
        for (int c = 0; c < 8; ++c)
          out[(size_t)gr * DD + c * 16 + (lane & 15)] = fmaxf(acc[i][c][v] + bv[c], 0.f);
      }
    }
  }
}

extern "C" void kernel_launch(void* const* d_in, const int* in_sizes, int n_in,
                              void* d_out, int out_size, void* d_ws, size_t ws_size,
                              hipStream_t stream) {
  const float* x      = (const float*)d_in[0];  // [N,128]
  const float* weight = (const float*)d_in[1];  // [R,128,128]
  const float* loop_w = (const float*)d_in[2];  // [128,128]
  const float* h_bias = (const float*)d_in[3];  // [128]
  const int*   src    = (const int*)d_in[4];    // [R,E]
  const int*   dst    = (const int*)d_in[5];    // [R,E]
  float* out = (float*)d_out;                   // [N,128]

  const int N = in_sizes[0] / DD;
  const int R = in_sizes[1] / (DD * DD);        // == RR == 4
  const int E = in_sizes[4] / R;
  const int RN = R * N, RE = R * E;

  char* p = (char*)d_ws;
  auto alloc = [&](size_t bytes) {
    char* q = p;
    p += (bytes + 63) & ~size_t(63);
    return q;
  };
  int* deg  = (int*)alloc((size_t)RN * 4);                      // [N][4] node-major
  int* slot = (int*)alloc((size_t)RN * CAP * 4);                // [N][64] node-major
  unsigned short* wt = (unsigned short*)alloc((size_t)DD * KT * 2);
  unsigned short* xb = (unsigned short*)alloc((size_t)(N + 1) * DD * 2);  // +zero row
  unsigned short* y  = (unsigned short*)alloc((size_t)N * KY * 2);

  hipMemsetAsync(deg, 0, (size_t)RN * 4, stream);

  int XB = ((N + 1) * 16 + 255) / 256;
  int WB = (DD * KT + 255) / 256;
  int FB = (RE + 255) / 256;
  prep<<<XB + WB + FB, 256, 0, stream>>>(x, weight, loop_w, src, dst,
                                         xb, wt, deg, slot, N, E, XB, WB);
  gather_agg<<<((size_t)N * 64 + 255) / 256, 256, 0, stream>>>(
      (const unsigned*)xb, slot, deg, (unsigned*)y, N);
  gemm_mfma<<<(N + 127) / 128, 256, 0, stream>>>(y, xb, wt, h_bias, out, N);
}